// Round 8
// baseline (13763.402 us; speedup 1.0000x reference)
//
#include <hip/hip_runtime.h>
#include <hip/hip_bf16.h>

#define VOCAB 32000
#define EMBED 512
#define ENCD  512
#define HID   1024
#define ATTN  128
#define SRC   1024
#define TGT   512
#define NB    32          // blocks for the per-step fused kernel

typedef __hip_bfloat16 bf16;
typedef _Float16 f16;
typedef __attribute__((ext_vector_type(2))) _Float16 f16x2;
typedef __attribute__((ext_vector_type(4))) _Float16 f16x4;
typedef __attribute__((ext_vector_type(8))) _Float16 f16x8;
typedef __attribute__((ext_vector_type(8))) short bf16x8v;
typedef __attribute__((ext_vector_type(4))) float f32x4;

// ---- workspace layout (float offsets), ~24.7 MB ----
#define OFF_EPH     0           // f16 [1024][128] enc_proj
#define OFF_G       65536       // f32 [512][4096] PERMUTED gate bases
#define OFF_HH      2162688     // f32 [513][1024] h history
#define OFF_CC      2688000     // f32 [1024] c state
#define OFF_INVD    2689024     // f32 [512]
#define OFF_CTXP    2689536     // f32 [32][512] ctx partials   (atomic)
#define OFF_DENP    2705920     // f32 [32] (+pad)              (atomic)
#define OFF_SLOTS   2705984     // u32 [32] barrier slots (+pad)(atomic)
#define OFF_WAHH    2706048     // f16 [128][1024] Wa_h
#define OFF_WHH     2771584     // f16 [4096][1024] permuted rows
#define OFF_WIHC    4868736     // f16 [4096][512]  permuted rows
#define OFF_ENCT    5917312     // f16 [512][1024]  enc transposed
// end = 6179456 floats = 24.7 MB

__device__ __forceinline__ float sigm(float x){ return 1.f/(1.f+__expf(-x)); }
__device__ __forceinline__ float tanh_f(float x){
  float ax = fabsf(x);
  float e = __expf(-2.f*ax);
  float r = (1.f - e) / (1.f + e);
  return copysignf(r, x);
}
__device__ __forceinline__ short f2bs(float x){
  union { bf16 h; short s; } u; u.h = __float2bfloat16(x); return u.s;
}
__device__ __forceinline__ bf16x8v cvt8(const float* p){
  float4 a = *reinterpret_cast<const float4*>(p);
  float4 b = *reinterpret_cast<const float4*>(p+4);
  bf16x8v r;
  r[0]=f2bs(a.x); r[1]=f2bs(a.y); r[2]=f2bs(a.z); r[3]=f2bs(a.w);
  r[4]=f2bs(b.x); r[5]=f2bs(b.y); r[6]=f2bs(b.z); r[7]=f2bs(b.w);
  return r;
}
__device__ __forceinline__ float aldf(const float* p){
  return __hip_atomic_load(p, __ATOMIC_RELAXED, __HIP_MEMORY_SCOPE_AGENT);
}
__device__ __forceinline__ void astf(float* p, float v){
  __hip_atomic_store(p, v, __ATOMIC_RELAXED, __HIP_MEMORY_SCOPE_AGENT);
}

// ---- grid barrier (r6-proven): no fences; syncthreads drains stores first ----
__device__ __forceinline__ void gridbar(unsigned* slots, unsigned id, int b, int tid){
  __syncthreads();
  if (tid == 0)
    __hip_atomic_store(&slots[b], id, __ATOMIC_RELAXED, __HIP_MEMORY_SCOPE_AGENT);
  if (tid < 64){
    while (true){
      unsigned v = __hip_atomic_load(&slots[tid & (NB-1)], __ATOMIC_RELAXED, __HIP_MEMORY_SCOPE_AGENT);
      if (__all((int)(v >= id))) break;
      __builtin_amdgcn_s_sleep(1);
    }
  }
  __syncthreads();
}

// ---- one-time: enc_proj[s][a] -> f16 (grid 64 x 128 thr) ----
__global__ void k_encproj(const float* __restrict__ enc, const float* __restrict__ Wa_enc,
                          f16* __restrict__ eph){
  __shared__ float eL[16][ENCD];
  int s0 = blockIdx.x*16, tid = threadIdx.x;
  #pragma unroll
  for (int i=0;i<16;i++){
    int li = tid + i*128;
    int t = li>>7, k4 = li&127;
    *reinterpret_cast<float4*>(&eL[t][k4*4]) =
      *reinterpret_cast<const float4*>(enc + (size_t)(s0+t)*ENCD + k4*4);
  }
  __syncthreads();
  const float* w = Wa_enc + (size_t)tid*ENCD;
  float acc[16];
  #pragma unroll
  for (int t=0;t<16;t++) acc[t]=0.f;
  for (int k4=0;k4<128;k4++){
    float4 wv = *reinterpret_cast<const float4*>(w + k4*4);
    #pragma unroll
    for (int t=0;t<16;t++){
      float4 e4 = *reinterpret_cast<const float4*>(&eL[t][k4*4]);
      acc[t] += wv.x*e4.x + wv.y*e4.y + wv.z*e4.z + wv.w*e4.w;
    }
  }
  #pragma unroll
  for (int t=0;t<16;t++) eph[(size_t)(s0+t)*ATTN + tid] = (f16)acc[t];
}

// ---- one-time: Gp[t][prow], prow = (j>>5)*128 + g*32 + (j&31) ----
__global__ void k_gbase(const int* __restrict__ sos, const int* __restrict__ tgt,
                        const float* __restrict__ embt, const float* __restrict__ W_ih,
                        const float* __restrict__ b_ih, const float* __restrict__ b_hh,
                        float* __restrict__ Gp){
  __shared__ float eL[16][EMBED];
  int tid = threadIdx.x;
  int t0 = blockIdx.y*16;
  #pragma unroll
  for (int i=0;i<8;i++){
    int li = tid + i*256;
    int t = li>>7, k4 = li&127;
    int tg = t0 + t;
    int tok = (tg==0) ? sos[0] : tgt[tg-1];
    *reinterpret_cast<float4*>(&eL[t][k4*4]) =
      *reinterpret_cast<const float4*>(embt + (size_t)tok*EMBED + k4*4);
  }
  __syncthreads();
  int r = blockIdx.x*256 + tid;
  int g = r>>10, j = r&1023;
  int prow = (j>>5)*128 + g*32 + (j&31);
  const float* w = W_ih + (size_t)r*(EMBED+ENCD);
  float base = b_ih[r] + b_hh[r];
  float acc[16];
  #pragma unroll
  for (int t=0;t<16;t++) acc[t]=0.f;
  for (int k4=0;k4<128;k4++){
    float4 wv = *reinterpret_cast<const float4*>(w + k4*4);
    #pragma unroll
    for (int t=0;t<16;t++){
      float4 e4 = *reinterpret_cast<const float4*>(&eL[t][k4*4]);
      acc[t] += wv.x*e4.x + wv.y*e4.y + wv.z*e4.z + wv.w*e4.w;
    }
  }
  #pragma unroll
  for (int t=0;t<16;t++) Gp[(size_t)(t0+t)*4096 + prow] = acc[t] + base;
}

// ---- one-time f16 conversions; weight rows permuted for NB=32 ----
__global__ void k_cvt_whh(const float* __restrict__ W, f16* __restrict__ out){
  int r = blockIdx.x;
  int g = r >> 10, j = r & 1023;
  int prow = (j>>5)*128 + g*32 + (j&31);
  int k0 = threadIdx.x*8;
  float4 a = *reinterpret_cast<const float4*>(W + (size_t)r*HID + k0);
  float4 c = *reinterpret_cast<const float4*>(W + (size_t)r*HID + k0 + 4);
  f16x8 v = { (f16)a.x,(f16)a.y,(f16)a.z,(f16)a.w,(f16)c.x,(f16)c.y,(f16)c.z,(f16)c.w };
  *reinterpret_cast<f16x8*>(out + (size_t)prow*HID + k0) = v;
}
__global__ void k_cvt_wihc(const float* __restrict__ W, f16* __restrict__ out){
  int r = blockIdx.x;
  int g = r >> 10, j = r & 1023;
  int prow = (j>>5)*128 + g*32 + (j&31);
  int k0 = threadIdx.x*8;
  float4 a = *reinterpret_cast<const float4*>(W + (size_t)r*(EMBED+ENCD) + EMBED + k0);
  float4 c = *reinterpret_cast<const float4*>(W + (size_t)r*(EMBED+ENCD) + EMBED + k0 + 4);
  f16x8 v = { (f16)a.x,(f16)a.y,(f16)a.z,(f16)a.w,(f16)c.x,(f16)c.y,(f16)c.z,(f16)c.w };
  *reinterpret_cast<f16x8*>(out + (size_t)prow*ENCD + k0) = v;
}
__global__ void k_cvt_wah(const float* __restrict__ W, f16* __restrict__ out){
  int r = blockIdx.x;                // 128 rows
  int k0 = threadIdx.x*8;            // 128 thr x 8
  float4 a = *reinterpret_cast<const float4*>(W + (size_t)r*HID + k0);
  float4 c = *reinterpret_cast<const float4*>(W + (size_t)r*HID + k0 + 4);
  f16x8 v = { (f16)a.x,(f16)a.y,(f16)a.z,(f16)a.w,(f16)c.x,(f16)c.y,(f16)c.z,(f16)c.w };
  *reinterpret_cast<f16x8*>(out + (size_t)r*HID + k0) = v;
}
// enc [1024][512] f32 -> encT [512][1024] f16
__global__ void k_cvt_encT(const float* __restrict__ enc, f16* __restrict__ out){
  __shared__ float tile[64][65];
  int s0 = blockIdx.x*64, d0 = blockIdx.y*64;
  int tid = threadIdx.x;
  #pragma unroll
  for (int i=0;i<16;i++){
    int idx = tid + i*256;
    int sl = idx>>6, dl = idx&63;
    tile[sl][dl] = enc[(size_t)(s0+sl)*ENCD + d0+dl];
  }
  __syncthreads();
  #pragma unroll
  for (int i=0;i<16;i++){
    int idx = tid + i*256;
    int dl = idx>>6, sl = idx&63;
    out[(size_t)(d0+dl)*SRC + s0+sl] = (f16)tile[sl][dl];
  }
}

// ---- one-time: slots=0, Hh[0]=h0, Cc=c0 (grid 32 x 128) ----
__global__ void k_prep0(const float* __restrict__ h0, const float* __restrict__ c0,
                        float* __restrict__ Hh, float* __restrict__ Cc,
                        unsigned* __restrict__ slots){
  int b = blockIdx.x, tid = threadIdx.x;
  if (b == 0 && tid < NB) slots[tid] = 0u;
  if (b < 8){ Hh[b*128 + tid] = h0[b*128 + tid]; Cc[b*128 + tid] = c0[b*128 + tid]; }
}

// ---- per step: ONE fused kernel, 32 blocks x 1024 thr, 1 internal barrier ----
__global__ __launch_bounds__(1024) void k_fused(int t,
    const f16* __restrict__ eph, const f16* __restrict__ encT,
    const f16* __restrict__ Wah_h, const f16* __restrict__ Whh_h,
    const f16* __restrict__ Wihc_h, const float* __restrict__ Gp,
    const float* __restrict__ v_a,
    float* __restrict__ Hh, float* __restrict__ Cc,
    float* __restrict__ ctxp, float* __restrict__ denp,
    unsigned* __restrict__ slots, float* __restrict__ Pout,
    float* __restrict__ invd)
{
  const int b = blockIdx.x, tid = threadIdx.x;
  __shared__ f16x2 hs2[512];        // h_t as f16 pairs
  __shared__ float vas[128];
  __shared__ float wah[128];
  __shared__ float psl[32];
  __shared__ f16x2 pslh[16];
  __shared__ float gacc[128];       // Whh·h for this block's 128 gate rows
  __shared__ float cp2[2][512];
  __shared__ f16x2 cs2[256];
  __shared__ float g2[128];
  __shared__ float invs;

  const int l8 = tid >> 3, q8 = tid & 7;        // matvec mapping: 128 rows x 8 lanes

  // ---- A0: load h_t (full, via launch-boundary coherence) + v_a ----
  if (tid < 256){
    float4 v0 = *reinterpret_cast<const float4*>(Hh + (size_t)t*HID + tid*4);
    hs2[tid*2]   = (f16x2){(f16)v0.x,(f16)v0.y};
    hs2[tid*2+1] = (f16x2){(f16)v0.z,(f16)v0.w};
  } else if (tid < 384){
    vas[tid-256] = v_a[tid-256];
  }
  __syncthreads();
  // ---- A1: wah = Wa_h·h (redundant per block; kills the wahp exchange) ----
  {
    const f16x8* wr = (const f16x8*)(Wah_h + (size_t)l8*HID + q8*128);
    float acc = 0.f;
    #pragma unroll
    for (int i = 0; i < 16; ++i){
      f16x8 wv = wr[i];
      const f16x2* wp = (const f16x2*)&wv;
      int k2 = q8*64 + i*4;
      acc = __builtin_amdgcn_fdot2(wp[0], hs2[k2+0], acc, false);
      acc = __builtin_amdgcn_fdot2(wp[1], hs2[k2+1], acc, false);
      acc = __builtin_amdgcn_fdot2(wp[2], hs2[k2+2], acc, false);
      acc = __builtin_amdgcn_fdot2(wp[3], hs2[k2+3], acc, false);
    }
    acc += __shfl_xor(acc,1); acc += __shfl_xor(acc,2); acc += __shfl_xor(acc,4);
    if (q8 == 0) wah[l8] = acc;
  }
  __syncthreads();
  // ---- A2: scores for this block's 32 src rows (32 rows x 32 lanes x 4 dims) ----
  {
    int srow = tid >> 5, lq = tid & 31;
    const f16x4* ep4 = (const f16x4*)(eph + (size_t)(b*32+srow)*ATTN);
    f16x4 e4 = ep4[lq];
    float sc = 0.f;
    #pragma unroll
    for (int u = 0; u < 4; ++u){
      int a = lq*4 + u;
      sc += vas[a]*tanh_f((float)e4[u] + wah[a]);
    }
    sc += __shfl_xor(sc,1); sc += __shfl_xor(sc,2); sc += __shfl_xor(sc,4);
    sc += __shfl_xor(sc,8); sc += __shfl_xor(sc,16);
    if (lq == 0){
      float pv = __expf(sc);
      psl[srow] = pv;
      Pout[(size_t)t*SRC + b*32 + srow] = pv;     // normal store (read post-kernel)
    }
  }
  __syncthreads();
  // ---- A3: pack ps to f16 pairs | den partial ----
  if (tid < 16) pslh[tid] = (f16x2){ (f16)psl[2*tid], (f16)psl[2*tid+1] };
  else if (tid >= 32 && tid < 64){
    float v = psl[tid-32];
    v += __shfl_xor(v,1); v += __shfl_xor(v,2); v += __shfl_xor(v,4);
    v += __shfl_xor(v,8); v += __shfl_xor(v,16);
    if (tid == 32) astf(&denp[b], v);
  }
  __syncthreads();
  // ---- A4: ctx partials over this block's 32 src rows (tid<512) ----
  if (tid < 512){
    const f16x8* er = (const f16x8*)(encT + (size_t)tid*SRC + b*32);
    float acc = 0.f;
    #pragma unroll
    for (int i = 0; i < 4; ++i){
      f16x8 ev = er[i];
      const f16x2* ep = (const f16x2*)&ev;
      acc = __builtin_amdgcn_fdot2(ep[0], pslh[i*4+0], acc, false);
      acc = __builtin_amdgcn_fdot2(ep[1], pslh[i*4+1], acc, false);
      acc = __builtin_amdgcn_fdot2(ep[2], pslh[i*4+2], acc, false);
      acc = __builtin_amdgcn_fdot2(ep[3], pslh[i*4+3], acc, false);
    }
    astf(&ctxp[b*512 + tid], acc);
  }
  // ---- A5: gacc = Whh·h for this block's 128 gate rows (all threads) ----
  {
    const f16x8* wr = (const f16x8*)(Whh_h + (size_t)(b*128 + l8)*HID + q8*128);
    float acc = 0.f;
    #pragma unroll
    for (int i = 0; i < 16; ++i){
      f16x8 wv = wr[i];
      const f16x2* wp = (const f16x2*)&wv;
      int k2 = q8*64 + i*4;
      acc = __builtin_amdgcn_fdot2(wp[0], hs2[k2+0], acc, false);
      acc = __builtin_amdgcn_fdot2(wp[1], hs2[k2+1], acc, false);
      acc = __builtin_amdgcn_fdot2(wp[2], hs2[k2+2], acc, false);
      acc = __builtin_amdgcn_fdot2(wp[3], hs2[k2+3], acc, false);
    }
    acc += __shfl_xor(acc,1); acc += __shfl_xor(acc,2); acc += __shfl_xor(acc,4);
    if (q8 == 0) gacc[l8] = acc;
  }
  // ---- the one in-kernel grid barrier ----
  gridbar(slots, (unsigned)(t+1), b, tid);
  // ---- B0: den reduce + ctx reduce ----
  if (tid < 32){
    float dv = aldf(&denp[tid]);
    dv += __shfl_xor(dv,1); dv += __shfl_xor(dv,2); dv += __shfl_xor(dv,4);
    dv += __shfl_xor(dv,8); dv += __shfl_xor(dv,16);
    if (tid == 0){ float iv = 1.f/dv; invs = iv; if (b == 0) invd[t] = iv; }
  }
  {
    int d = tid & 511, g = tid >> 9;
    float acc = 0.f;
    #pragma unroll
    for (int p = 0; p < 16; ++p) acc += aldf(&ctxp[(g*16+p)*512 + d]);
    cp2[g][d] = acc;
  }
  __syncthreads();
  if (tid < 256){
    float iv = invs;
    int d2 = tid*2;
    cs2[tid] = (f16x2){ (f16)((cp2[0][d2]+cp2[1][d2])*iv),
                        (f16)((cp2[0][d2+1]+cp2[1][d2+1])*iv) };
  }
  __syncthreads();
  // ---- B1: gates = gacc + Wihc·ctx + G ----
  {
    const f16x8* wr = (const f16x8*)(Wihc_h + (size_t)(b*128 + l8)*ENCD + q8*64);
    float acc = 0.f;
    #pragma unroll
    for (int i = 0; i < 8; ++i){
      f16x8 wv = wr[i];
      const f16x2* wp = (const f16x2*)&wv;
      int k2 = q8*32 + i*4;
      acc = __builtin_amdgcn_fdot2(wp[0], cs2[k2+0], acc, false);
      acc = __builtin_amdgcn_fdot2(wp[1], cs2[k2+1], acc, false);
      acc = __builtin_amdgcn_fdot2(wp[2], cs2[k2+2], acc, false);
      acc = __builtin_amdgcn_fdot2(wp[3], cs2[k2+3], acc, false);
    }
    acc += __shfl_xor(acc,1); acc += __shfl_xor(acc,2); acc += __shfl_xor(acc,4);
    if (q8 == 0) g2[l8] = acc + gacc[l8] + Gp[(size_t)t*4096 + b*128 + l8];
  }
  __syncthreads();
  // ---- B2: LSTM pointwise; h_{t+1} slice via normal store (launch boundary) ----
  if (tid < 32){
    int jl = b*32 + tid;
    float gi = g2[tid], gf = g2[32+tid], gg = g2[64+tid], go = g2[96+tid];
    float cn = sigm(gf)*Cc[jl] + sigm(gi)*tanh_f(gg);
    float hn = sigm(go)*tanh_f(cn);
    Cc[jl] = cn;
    Hh[(size_t)(t+1)*HID + jl] = hn;
  }
}

// ---- epilogue: logits = H @ W_out^T + b_out (bf16 MFMA, f32 in/out) ----
__global__ __launch_bounds__(256) void k_gemm(const float* __restrict__ A, const float* __restrict__ B,
                                              const float* __restrict__ bias, float* __restrict__ C){
  int bn = blockIdx.x, bm = blockIdx.y;
  int tid = threadIdx.x;
  int wid = tid>>6, lane = tid&63;
  int wr = wid>>1, wc = wid&1;
  int rowf = lane&15, kg = lane>>4;
  const int m_base = bm*128 + wr*64;
  const int n_base = bn*128 + wc*64;
  const float* Ap = A + (size_t)(m_base + rowf)*HID + kg*8;
  const float* Bp = B + (size_t)(n_base + rowf)*HID + kg*8;
  f32x4 acc[4][4];
  #pragma unroll
  for (int i=0;i<4;i++)
    #pragma unroll
    for (int jv=0;jv<4;jv++) acc[i][jv] = (f32x4){0.f,0.f,0.f,0.f};
  for (int kk=0; kk<HID; kk+=32){
    bf16x8v av[4], bv[4];
    #pragma unroll
    for (int mt=0;mt<4;mt++) av[mt] = cvt8(Ap + (size_t)mt*16*HID + kk);
    #pragma unroll
    for (int nt=0;nt<4;nt++) bv[nt] = cvt8(Bp + (size_t)nt*16*HID + kk);
    #pragma unroll
    for (int mt=0;mt<4;mt++)
      #pragma unroll
      for (int nt=0;nt<4;nt++)
        acc[mt][nt] = __builtin_amdgcn_mfma_f32_16x16x32_bf16(av[mt], bv[nt], acc[mt][nt], 0,0,0);
  }
  #pragma unroll
  for (int mt=0;mt<4;mt++){
    #pragma unroll
    for (int nt=0;nt<4;nt++){
      int n = n_base + nt*16 + rowf;
      float bo = bias[n];
      #pragma unroll
      for (int i=0;i<4;i++){
        int m = m_base + mt*16 + kg*4 + i;
        C[(size_t)m*VOCAB + n] = acc[mt][nt][i] + bo;
      }
    }
  }
}

// ---- epilogue: attn = P * invden, in place on d_out ----
__global__ void k_attnorm(float* __restrict__ out, const float* __restrict__ invden){
  int idx = blockIdx.x*256 + threadIdx.x;
  out[idx] = out[idx]*invden[idx>>10];
}

extern "C" void kernel_launch(void* const* d_in, const int* in_sizes, int n_in,
                              void* d_out, int out_size, void* d_ws, size_t ws_size,
                              hipStream_t stream){
  const float* enc    = (const float*)d_in[0];
  const float* h0     = (const float*)d_in[1];
  const float* c0     = (const float*)d_in[2];
  const int*   sos    = (const int*)d_in[3];
  const int*   tgt    = (const int*)d_in[4];
  const float* embt   = (const float*)d_in[5];
  const float* Wa_enc = (const float*)d_in[6];
  const float* Wa_h   = (const float*)d_in[7];
  const float* v_a    = (const float*)d_in[8];
  const float* W_ih   = (const float*)d_in[9];
  const float* W_hh   = (const float*)d_in[10];
  const float* b_ih   = (const float*)d_in[11];
  const float* b_hh   = (const float*)d_in[12];
  const float* W_out  = (const float*)d_in[13];
  const float* b_out  = (const float*)d_in[14];

  float* ws    = (float*)d_ws;
  f16*   eph   = (f16*)(ws + OFF_EPH);
  float* Gp    = ws + OFF_G;
  float* Hh    = ws + OFF_HH;
  float* Cc    = ws + OFF_CC;
  float* invd  = ws + OFF_INVD;
  float* ctxp  = ws + OFF_CTXP;
  float* denp  = ws + OFF_DENP;
  unsigned* slots = (unsigned*)(ws + OFF_SLOTS);
  f16* Wah_h   = (f16*)(ws + OFF_WAHH);
  f16* Whh_h   = (f16*)(ws + OFF_WHH);
  f16* Wihc_h  = (f16*)(ws + OFF_WIHC);
  f16* encT    = (f16*)(ws + OFF_ENCT);

  float* out_logits = (float*)d_out;
  float* out_attn   = out_logits + (size_t)TGT*VOCAB;

  k_encproj <<<64, 128, 0, stream>>>(enc, Wa_enc, eph);
  k_gbase   <<<dim3(16, 32), 256, 0, stream>>>(sos, tgt, embt, W_ih, b_ih, b_hh, Gp);
  k_cvt_whh <<<4096, 128, 0, stream>>>(W_hh, Whh_h);
  k_cvt_wihc<<<4096, 64, 0, stream>>>(W_ih, Wihc_h);
  k_cvt_wah <<<128, 128, 0, stream>>>(Wa_h, Wah_h);
  k_cvt_encT<<<dim3(16, 8), 256, 0, stream>>>(enc, encT);
  k_prep0   <<<NB, 128, 0, stream>>>(h0, c0, Hh, Cc, slots);

  for (int t = 0; t < TGT; ++t){
    k_fused<<<NB, 1024, 0, stream>>>(t, eph, encT, Wah_h, Whh_h, Wihc_h, Gp, v_a,
                                     Hh, Cc, ctxp, denp, slots, out_attn, invd);
  }

  k_gemm   <<<dim3(250, 4), 256, 0, stream>>>(Hh + HID, W_out, b_out, out_logits);
  k_attnorm<<<2048, 256, 0, stream>>>(out_attn, invd);
}